// Round 4
// baseline (187.524 us; speedup 1.0000x reference)
//
#include <hip/hip_runtime.h>

// VQ nearest-neighbor via f16-split MFMA: N=65536 queries, DIM=64, K=1024.
// dist = csq[k] - 2*dot(z,c); dot computed by 2-term f16 split:
//   z = zh + 2^-11*zl', c = ch + 2^-11*cl'  (zl',cl' = residual * 2^11,
//   pre-scaled so f16 residuals stay normal-range)
//   dot ~= zh.ch + 2^-11*(zh.cl' + zl'.ch)   [ll term ~3e-8, dropped]
// => ~22 mantissa bits; dist error ~2e-5, same order as the fp32 path's own
// deviation from the numpy reference (rounds 1-3: absmax 0 at 3 orderings).
//
// Structure: wave = 16 queries x all 1024 codes. A-fragments (h+l, both
// K-steps) live in 16 VGPRs for the whole sweep -- no LDS in the inner loop.
// B-fragments = 16B global loads from pre-split f16 codebook (256 KB, L2-hot).
// Per 16-code tile: 6 MFMA (16x16x32_f16) + running per-lane argmin on the
// C-fragment (col=lane&15, row=quad*4+reg), then shfl_xor quad-reduction.

typedef _Float16 half8 __attribute__((ext_vector_type(8)));
typedef float float4v __attribute__((ext_vector_type(4)));

constexpr int KCODES = 1024;
constexpr int DIM = 64;
constexpr int QPB = 64;    // queries per block (4 waves x 16)
constexpr int BLOCK = 256;

// d_ws layout
constexpr size_t WS_CSQ = 0;        // 1024 f32   = 4 KB
constexpr size_t WS_CBH = 4096;     // 1024x64 f16 = 128 KB
constexpr size_t WS_CBL = 135168;   // 1024x64 f16 = 128 KB

// Pre-split the codebook into (ch, cl*2^11) f16 arrays + fp32 norms.
__global__ __launch_bounds__(64) void prep_kernel(
    const float* __restrict__ cb, _Float16* __restrict__ cbh,
    _Float16* __restrict__ cbl, float* __restrict__ csq) {
  const int k = blockIdx.x * 64 + threadIdx.x;
  const float4* c4 = (const float4*)(cb + (size_t)k * DIM);
  _Float16 hb[DIM], lb[DIM];
  float s0 = 0.f, s1 = 0.f, s2 = 0.f, s3 = 0.f;
#pragma unroll
  for (int e = 0; e < DIM / 4; ++e) {
    const float4 v = c4[e];
    s0 = fmaf(v.x, v.x, s0); s1 = fmaf(v.y, v.y, s1);
    s2 = fmaf(v.z, v.z, s2); s3 = fmaf(v.w, v.w, s3);
    const float x[4] = {v.x, v.y, v.z, v.w};
#pragma unroll
    for (int j = 0; j < 4; ++j) {
      const _Float16 h = (_Float16)x[j];
      hb[4 * e + j] = h;
      lb[4 * e + j] = (_Float16)((x[j] - (float)h) * 2048.0f);
    }
  }
  csq[k] = (s0 + s1) + (s2 + s3);
#pragma unroll
  for (int j = 0; j < DIM / 8; ++j) {
    ((half8*)(cbh + (size_t)k * DIM))[j] = *(half8*)(hb + 8 * j);
    ((half8*)(cbl + (size_t)k * DIM))[j] = *(half8*)(lb + 8 * j);
  }
}

__global__ __launch_bounds__(BLOCK) void vq_mfma(
    const float* __restrict__ z, const float4* __restrict__ cb4,
    const _Float16* __restrict__ cbh, const _Float16* __restrict__ cbl,
    const float* __restrict__ csq_g, float4* __restrict__ out4) {
  __shared__ float scsq[KCODES];
  __shared__ int sidx[QPB];

  const int tid = threadIdx.x;
  const int lane = tid & 63;
  const int wave = tid >> 6;
  const int m = lane & 15;     // A: query row / B: code col / C: col
  const int quad = lane >> 4;  // k-offset group; C rows quad*4..+3

  // Stage csq once (256 x float4 = 4 KB, coalesced).
  ((float4*)scsq)[tid] = ((const float4*)csq_g)[tid];

  // A-fragments: this wave's 16 queries, resident for the whole code sweep.
  // A[m=lane&15][k=quad*8+j]; K-step0 dims 0..31, step1 dims 32..63.
  const int qbase = blockIdx.x * QPB + wave * 16;
  const float* zrow = z + (size_t)(qbase + m) * DIM + quad * 8;
  const float4 p0 = ((const float4*)zrow)[0];
  const float4 p1 = ((const float4*)zrow)[1];
  const float4 p2 = ((const float4*)(zrow + 32))[0];
  const float4 p3 = ((const float4*)(zrow + 32))[1];
  const float zf0[8] = {p0.x, p0.y, p0.z, p0.w, p1.x, p1.y, p1.z, p1.w};
  const float zf1[8] = {p2.x, p2.y, p2.z, p2.w, p3.x, p3.y, p3.z, p3.w};
  half8 ah0, al0, ah1, al1;
#pragma unroll
  for (int j = 0; j < 8; ++j) {
    const _Float16 h0 = (_Float16)zf0[j];
    ah0[j] = h0;
    al0[j] = (_Float16)((zf0[j] - (float)h0) * 2048.0f);
    const _Float16 h1 = (_Float16)zf1[j];
    ah1[j] = h1;
    al1[j] = (_Float16)((zf1[j] - (float)h1) * 2048.0f);
  }

  __syncthreads();  // scsq visible

  // B-fragment base: code row = t*16 + m, dims quad*8.. (16B f16 loads).
  const _Float16* bh_p = cbh + (size_t)m * DIM + quad * 8;
  const _Float16* bl_p = cbl + (size_t)m * DIM + quad * 8;

  float best[4] = {3.402823466e38f, 3.402823466e38f, 3.402823466e38f,
                   3.402823466e38f};
  int bestk[4] = {0, 0, 0, 0};

#pragma unroll 4
  for (int t = 0; t < KCODES / 16; ++t) {
    const half8 bh0 = *(const half8*)(bh_p + t * 16 * DIM);
    const half8 bh1 = *(const half8*)(bh_p + t * 16 * DIM + 32);
    const half8 bl0 = *(const half8*)(bl_p + t * 16 * DIM);
    const half8 bl1 = *(const half8*)(bl_p + t * 16 * DIM + 32);

    float4v accm = {0.f, 0.f, 0.f, 0.f};
    float4v accx = {0.f, 0.f, 0.f, 0.f};
    accm = __builtin_amdgcn_mfma_f32_16x16x32_f16(ah0, bh0, accm, 0, 0, 0);
    accm = __builtin_amdgcn_mfma_f32_16x16x32_f16(ah1, bh1, accm, 0, 0, 0);
    accx = __builtin_amdgcn_mfma_f32_16x16x32_f16(ah0, bl0, accx, 0, 0, 0);
    accx = __builtin_amdgcn_mfma_f32_16x16x32_f16(ah1, bl1, accx, 0, 0, 0);
    accx = __builtin_amdgcn_mfma_f32_16x16x32_f16(al0, bh0, accx, 0, 0, 0);
    accx = __builtin_amdgcn_mfma_f32_16x16x32_f16(al1, bh1, accx, 0, 0, 0);

    const int k = t * 16 + m;         // this lane's code column
    const float cs = scsq[k];
#pragma unroll
    for (int r = 0; r < 4; ++r) {
      float dist = fmaf(-2.0f, accm[r], cs);
      dist = fmaf(-9.765625e-4f, accx[r], dist);  // -2 * 2^-11
      // k monotone in t for fixed lane: strict < keeps lowest-k minimum.
      if (dist < best[r]) { best[r] = dist; bestk[r] = k; }
    }
  }

  // Cross-lane argmin within each 16-lane quad (ties -> lower k).
#pragma unroll
  for (int r = 0; r < 4; ++r) {
    float b = best[r];
    int bk = bestk[r];
#pragma unroll
    for (int s = 1; s < 16; s <<= 1) {
      const float ob = __shfl_xor(b, s);
      const int obk = __shfl_xor(bk, s);
      if (ob < b || (ob == b && obk < bk)) { b = ob; bk = obk; }
    }
    if (m == 0) sidx[wave * 16 + quad * 4 + r] = bk;  // row = quad*4+r
  }
  __syncthreads();

  // Gather winning fp32 codebook rows; coalesced float4 writes.
  const size_t obase = (size_t)blockIdx.x * QPB * (DIM / 4);
#pragma unroll
  for (int r = 0; r < QPB * (DIM / 4) / BLOCK; ++r) {
    const int f = r * BLOCK + tid;
    const int q = f >> 4, e = f & 15;
    out4[obase + f] = cb4[(size_t)sidx[q] * (DIM / 4) + e];
  }
}

extern "C" void kernel_launch(void* const* d_in, const int* in_sizes, int n_in,
                              void* d_out, int out_size, void* d_ws, size_t ws_size,
                              hipStream_t stream) {
  const float* z = (const float*)d_in[0];
  const float* cb = (const float*)d_in[1];
  float* out = (float*)d_out;
  char* ws = (char*)d_ws;
  float* csq = (float*)(ws + WS_CSQ);
  _Float16* cbh = (_Float16*)(ws + WS_CBH);
  _Float16* cbl = (_Float16*)(ws + WS_CBL);

  const int nq = in_sizes[0] / DIM;  // 65536
  prep_kernel<<<KCODES / 64, 64, 0, stream>>>(cb, cbh, cbl, csq);
  vq_mfma<<<nq / QPB, BLOCK, 0, stream>>>(z, (const float4*)cb, cbh, cbl, csq,
                                          (float4*)out);
}

// Round 5
// 103.496 us; speedup vs baseline: 1.8119x; 1.8119x over previous
//
#include <hip/hip_runtime.h>

// VQ nearest-neighbor via f16-split MFMA. N=65536 queries, DIM=64, K=1024.
// v = dot(z,c) - csq[k]/2; argmax_k v  ==  argmin_k ||z-c||^2.
// 2-term f16 split (as round 4, absmax=0): dot ~= zh.ch + 2^-11(zh.cl'+zl'.ch).
//
// Round-5 structure (fixes round 4's B-fetch bound: MfmaUtil 8 / VALU 13):
//  * 64 queries per wave: A-fragments (4 qtiles x 2 ktiles x h,l = 16 half8 =
//    64 VGPR) resident for the whole sweep -> L2 B-traffic /4 (268 MB).
//  * K-split x2 within a block keeps 2048 waves (2/SIMD) at no traffic cost.
//  * Codebook pre-swizzled to FRAGMENT ORDER by prep: lane l of tile t loads
//    bytes t*4096 + l*16 -> every B-load is one contiguous coalesced 1 KB
//    wave-load (round 4 scattered 16 B x 64 lanes over 2 KB = 16 lines/load).
//  * -csq/2 folded into the MFMA C-operand (saves 1 FMA/candidate, no
//    per-tile acc-init movs). No __syncthreads in the K-loop -> loads stay
//    in flight across iterations.

typedef _Float16 half8 __attribute__((ext_vector_type(8)));
typedef float float4v __attribute__((ext_vector_type(4)));

constexpr int KCODES = 1024;
constexpr int DIM = 64;
constexpr int BLOCK = 256;

// d_ws layout
constexpr size_t WS_CSQN = 0;      // 1024 f32 (-csq/2)            = 4 KB
constexpr size_t WS_CBF = 4096;    // fragment-ordered split cb f16 = 256 KB

// Fragment-ordered split codebook:
// cbf[((t*2+kt)*2+hl)*512 + lane*8 + j], lane = quad*16+m, code = t*16+m,
// dim = kt*32 + quad*8 + j. hl=0: f16 high part; hl=1: residual * 2^11.
__global__ __launch_bounds__(BLOCK) void prep_kernel(
    const float* __restrict__ cb, _Float16* __restrict__ cbf,
    float* __restrict__ csqn) {
  const int k = blockIdx.x * BLOCK + threadIdx.x;  // grid 4 x 256 = 1024
  const int t = k >> 4, m = k & 15;
  const float4* c4 = (const float4*)(cb + (size_t)k * DIM);
  float x[DIM];
  float s0 = 0.f, s1 = 0.f, s2 = 0.f, s3 = 0.f;
#pragma unroll
  for (int e = 0; e < DIM / 4; ++e) {
    const float4 v = c4[e];
    x[4 * e + 0] = v.x; x[4 * e + 1] = v.y;
    x[4 * e + 2] = v.z; x[4 * e + 3] = v.w;
    s0 = fmaf(v.x, v.x, s0); s1 = fmaf(v.y, v.y, s1);
    s2 = fmaf(v.z, v.z, s2); s3 = fmaf(v.w, v.w, s3);
  }
  csqn[k] = -0.5f * ((s0 + s1) + (s2 + s3));
#pragma unroll
  for (int kt = 0; kt < 2; ++kt)
#pragma unroll
    for (int quad = 0; quad < 4; ++quad) {
      half8 h8, l8;
#pragma unroll
      for (int j = 0; j < 8; ++j) {
        const float xv = x[kt * 32 + quad * 8 + j];
        const _Float16 h = (_Float16)xv;
        h8[j] = h;
        l8[j] = (_Float16)((xv - (float)h) * 2048.0f);
      }
      const int lane = quad * 16 + m;
      *(half8*)(cbf + (size_t)((t * 2 + kt) * 2 + 0) * 512 + lane * 8) = h8;
      *(half8*)(cbf + (size_t)((t * 2 + kt) * 2 + 1) * 512 + lane * 8) = l8;
    }
}

// Block = 256 thr = 4 waves = 2 query-groups (64 q each) x 2 K-halves.
__global__ __launch_bounds__(BLOCK, 2) void vq_mfma(
    const float* __restrict__ z, const float4* __restrict__ cb4,
    const _Float16* __restrict__ cbf, const float* __restrict__ csqn_g,
    float4* __restrict__ out4) {
  __shared__ float scsqn[KCODES];
  __shared__ float rv[2][128];
  __shared__ int rk[2][128];
  __shared__ int sidx[128];

  const int tid = threadIdx.x;
  const int lane = tid & 63;
  const int wave = tid >> 6;
  const int qg = wave & 1;    // query group (64 queries)
  const int kh = wave >> 1;   // K half (512 codes)
  const int m = lane & 15;
  const int quad = lane >> 4;

  ((float4*)scsqn)[tid] = ((const float4*)csqn_g)[tid];

  // A-fragments: 4 qtiles x 2 ktiles, h + l. A[m][k=quad*8+j].
  const int qbase = blockIdx.x * 128 + qg * 64;
  half8 ah[4][2], al[4][2];
#pragma unroll
  for (int qt = 0; qt < 4; ++qt) {
    const float* zr = z + (size_t)(qbase + qt * 16 + m) * DIM + quad * 8;
#pragma unroll
    for (int kt = 0; kt < 2; ++kt) {
      const float4 p0 = ((const float4*)(zr + kt * 32))[0];
      const float4 p1 = ((const float4*)(zr + kt * 32))[1];
      const float zf[8] = {p0.x, p0.y, p0.z, p0.w, p1.x, p1.y, p1.z, p1.w};
#pragma unroll
      for (int j = 0; j < 8; ++j) {
        const _Float16 h = (_Float16)zf[j];
        ah[qt][kt][j] = h;
        al[qt][kt][j] = (_Float16)((zf[j] - (float)h) * 2048.0f);
      }
    }
  }

  __syncthreads();  // scsqn visible

  const float4v zvec = {0.f, 0.f, 0.f, 0.f};
  float best[4][4];
  int bestk[4][4];
#pragma unroll
  for (int qt = 0; qt < 4; ++qt)
#pragma unroll
    for (int r = 0; r < 4; ++r) { best[qt][r] = -3.402823466e38f; bestk[qt][r] = 0; }

  // B base: this wave's K-half, fragment-ordered -> contiguous 1 KB loads.
  const _Float16* bbase = cbf + (size_t)kh * 65536 + lane * 8;

#pragma unroll 2
  for (int t = 0; t < 32; ++t) {
    const _Float16* pt = bbase + (size_t)t * 2048;
    const half8 bh0 = *(const half8*)(pt);          // kt0, h
    const half8 bl0 = *(const half8*)(pt + 512);    // kt0, l
    const half8 bh1 = *(const half8*)(pt + 1024);   // kt1, h
    const half8 bl1 = *(const half8*)(pt + 1536);   // kt1, l

    const int k16 = kh * 512 + t * 16 + m;          // this lane's code column
    const float c = scsqn[k16];
    const float4v cvec = {c, c, c, c};

#pragma unroll
    for (int qt = 0; qt < 4; ++qt) {
      float4v am = __builtin_amdgcn_mfma_f32_16x16x32_f16(ah[qt][0], bh0, cvec, 0, 0, 0);
      am = __builtin_amdgcn_mfma_f32_16x16x32_f16(ah[qt][1], bh1, am, 0, 0, 0);
      float4v ax = __builtin_amdgcn_mfma_f32_16x16x32_f16(ah[qt][0], bl0, zvec, 0, 0, 0);
      ax = __builtin_amdgcn_mfma_f32_16x16x32_f16(ah[qt][1], bl1, ax, 0, 0, 0);
      ax = __builtin_amdgcn_mfma_f32_16x16x32_f16(al[qt][0], bh0, ax, 0, 0, 0);
      ax = __builtin_amdgcn_mfma_f32_16x16x32_f16(al[qt][1], bh1, ax, 0, 0, 0);
#pragma unroll
      for (int r = 0; r < 4; ++r) {
        const float v = fmaf(4.8828125e-4f, ax[r], am[r]);  // 2^-11
        // k ascending in t per lane: strict > keeps lowest-k maximum.
        if (v > best[qt][r]) { best[qt][r] = v; bestk[qt][r] = k16; }
      }
    }
  }

  // Cross-lane argmax over the 16 cols (m) in each quad; ties -> lower k.
#pragma unroll
  for (int qt = 0; qt < 4; ++qt)
#pragma unroll
    for (int r = 0; r < 4; ++r) {
      float b = best[qt][r];
      int bk = bestk[qt][r];
#pragma unroll
      for (int s = 1; s < 16; s <<= 1) {
        const float ob = __shfl_xor(b, s);
        const int obk = __shfl_xor(bk, s);
        if (ob > b || (ob == b && obk < bk)) { b = ob; bk = obk; }
      }
      if (m == 0) {
        const int qb = qg * 64 + qt * 16 + quad * 4 + r;  // row = quad*4+r
        rv[kh][qb] = b;
        rk[kh][qb] = bk;
      }
    }
  __syncthreads();

  // Combine K-halves (strict >: ties -> half 0 = lower k).
  if (tid < 128) {
    const float v0 = rv[0][tid], v1 = rv[1][tid];
    sidx[tid] = (v1 > v0) ? rk[1][tid] : rk[0][tid];
  }
  __syncthreads();

  // Gather winning fp32 codebook rows; coalesced float4 writes.
  const size_t obase = (size_t)blockIdx.x * 128 * (DIM / 4);
#pragma unroll
  for (int f0 = 0; f0 < 128 * (DIM / 4); f0 += BLOCK) {
    const int f = f0 + tid;
    const int q = f >> 4, e = f & 15;
    out4[obase + f] = cb4[(size_t)sidx[q] * (DIM / 4) + e];
  }
}

extern "C" void kernel_launch(void* const* d_in, const int* in_sizes, int n_in,
                              void* d_out, int out_size, void* d_ws, size_t ws_size,
                              hipStream_t stream) {
  const float* z = (const float*)d_in[0];
  const float* cb = (const float*)d_in[1];
  char* ws = (char*)d_ws;
  float* csqn = (float*)(ws + WS_CSQN);
  _Float16* cbf = (_Float16*)(ws + WS_CBF);

  const int nq = in_sizes[0] / DIM;  // 65536
  prep_kernel<<<KCODES / BLOCK, BLOCK, 0, stream>>>(cb, cbf, csqn);
  vq_mfma<<<nq / 128, BLOCK, 0, stream>>>(z, (const float4*)cb, cbf, csqn,
                                          (float4*)d_out);
}